// Round 1
// 118.847 us; speedup vs baseline: 1.0233x; 1.0233x over previous
//
#include <hip/hip_runtime.h>

// Problem constants
#define BB 4
#define SS 2048
#define DM 256
#define NH 4
#define DH 64
#define NROW (BB*SS)              // 8192
#define NE   (3*DM)               // 768
#define BH   (BB*NH)              // 16
#define HEAD_ELEMS (BH*SS*DH)     // 2097152 per tensor
#define NQROWS (BH*SS)            // 32768

typedef _Float16 half_t;
typedef __attribute__((ext_vector_type(8))) _Float16 half8;
typedef __attribute__((ext_vector_type(4))) _Float16 half4;
typedef __attribute__((ext_vector_type(4))) float floatx4;

#define KPAD 72                   // LDS stride in halfs (144 B, 16B-aligned rows)

// exp2-domain softmax: scores are pre-scaled by 1/sqrt(64) * log2(e)
#define QK_SCALE 0.18033688011112042f
#define EXP2(x) __builtin_amdgcn_exp2f(x)
#define DEFER_THR 8.0f            // skip O-rescale while max grows < 8 (log2 units)

// ---------------------------------------------------------------------------
// prep: one-shot conversion  x -> (x_hi, x_lo) fp16,  W -> fp16.
// grid 2048 x 256: thread gtid handles x[gtid*4..+3]; first 49152 also W.
// ---------------------------------------------------------------------------
__global__ __launch_bounds__(256) void prep(const float* __restrict__ x,
                                            const float* __restrict__ W,
                                            half_t* __restrict__ xh,
                                            half_t* __restrict__ xl,
                                            half_t* __restrict__ wh) {
    int gtid = blockIdx.x * 256 + threadIdx.x;    // 0..524287
    {
        int i = gtid * 4;
        float4 v = *(const float4*)&x[i];
        half4 h, l;
        h.x = (half_t)v.x; l.x = (half_t)(v.x - (float)h.x);
        h.y = (half_t)v.y; l.y = (half_t)(v.y - (float)h.y);
        h.z = (half_t)v.z; l.z = (half_t)(v.z - (float)h.z);
        h.w = (half_t)v.w; l.w = (half_t)(v.w - (float)h.w);
        *(half4*)&xh[i] = h;
        *(half4*)&xl[i] = l;
    }
    if (gtid < NE * DM / 4) {
        int i = gtid * 4;
        float4 v = *(const float4*)&W[i];
        half4 h;
        h.x = (half_t)v.x; h.y = (half_t)v.y;
        h.z = (half_t)v.z; h.w = (half_t)v.w;
        *(half4*)&wh[i] = h;
    }
}

// ---------------------------------------------------------------------------
// QKV projection, fp16 MFMA, hi/lo-split x (exact x, only W rounded).
// Epilogue: q scaled by 1/8*log2e (exp2-domain attention); k scatter;
// v transposes through LDS -> coalesced vt.
// ---------------------------------------------------------------------------
__global__ __launch_bounds__(256) void qkv_proj(const half_t* __restrict__ xh,
                                                const half_t* __restrict__ xl,
                                                const half_t* __restrict__ whg,
                                                const float* __restrict__ bias,
                                                half_t* __restrict__ qh,
                                                half_t* __restrict__ kh,
                                                half_t* __restrict__ vt) {
    __shared__ __align__(16) half_t Xh[64 * KPAD];
    __shared__ __align__(16) half_t Xl[64 * KPAD];
    __shared__ __align__(16) half_t Wh[64 * KPAD];

    const int rb   = blockIdx.x * 64;
    const int nb   = blockIdx.y * 64;
    const int tid  = threadIdx.x;
    const int wid  = tid >> 6;
    const int lane = tid & 63;
    const int quad = lane >> 4;
    const int col  = lane & 15;

    floatx4 acc[4];
    #pragma unroll
    for (int t = 0; t < 4; ++t) acc[t] = (floatx4){0.f, 0.f, 0.f, 0.f};

    for (int k0 = 0; k0 < DM; k0 += 64) {
        __syncthreads();
        #pragma unroll
        for (int i = 0; i < 2; ++i) {
            int gi = tid + 256 * i;        // 0..511
            int r  = gi >> 3;              // 0..63
            int c8 = (gi & 7) * 8;         // 0..56
            *(half8*)&Xh[r * KPAD + c8] = *(const half8*)&xh[(size_t)(rb + r) * DM + k0 + c8];
            *(half8*)&Xl[r * KPAD + c8] = *(const half8*)&xl[(size_t)(rb + r) * DM + k0 + c8];
            *(half8*)&Wh[r * KPAD + c8] = *(const half8*)&whg[(size_t)(nb + r) * DM + k0 + c8];
        }
        __syncthreads();

        half8 ah0 = *(const half8*)&Xh[(wid * 16 + col) * KPAD + quad * 8];
        half8 ah1 = *(const half8*)&Xh[(wid * 16 + col) * KPAD + 32 + quad * 8];
        half8 al0 = *(const half8*)&Xl[(wid * 16 + col) * KPAD + quad * 8];
        half8 al1 = *(const half8*)&Xl[(wid * 16 + col) * KPAD + 32 + quad * 8];

        #pragma unroll
        for (int t = 0; t < 4; ++t) {
            half8 bh0 = *(const half8*)&Wh[(t * 16 + col) * KPAD + quad * 8];
            half8 bh1 = *(const half8*)&Wh[(t * 16 + col) * KPAD + 32 + quad * 8];
            acc[t] = __builtin_amdgcn_mfma_f32_16x16x32_f16(ah0, bh0, acc[t], 0, 0, 0);
            acc[t] = __builtin_amdgcn_mfma_f32_16x16x32_f16(ah1, bh1, acc[t], 0, 0, 0);
            acc[t] = __builtin_amdgcn_mfma_f32_16x16x32_f16(al0, bh0, acc[t], 0, 0, 0);
            acc[t] = __builtin_amdgcn_mfma_f32_16x16x32_f16(al1, bh1, acc[t], 0, 0, 0);
        }
    }

    const int part = nb >> 8;           // block-uniform: 0=q 1=k 2=v
    const int mloc = wid * 16 + quad * 4;
    if (part != 2) {
        #pragma unroll
        for (int t = 0; t < 4; ++t) {
            int e    = nb + t * 16 + col;
            float be = bias[e];
            int dm   = e & 255;
            int h    = dm >> 6;
            int dh   = dm & 63;
            #pragma unroll
            for (int r = 0; r < 4; ++r) {
                int row = rb + mloc + r;
                int b   = row >> 11;
                int s   = row & 2047;
                int bh_ = b * NH + h;
                float val = acc[t][r] + be;
                if (part == 0) {
                    qh[((size_t)bh_ * SS + s) * DH + dh] = (half_t)(val * QK_SCALE);
                } else {
                    kh[((size_t)bh_ * SS + s) * DH + dh] = (half_t)val;
                }
            }
        }
    } else {
        __syncthreads();
        #pragma unroll
        for (int t = 0; t < 4; ++t) {
            int e    = nb + t * 16 + col;
            float be = bias[e];
            #pragma unroll
            for (int r = 0; r < 4; ++r)
                Xh[(t * 16 + col) * KPAD + mloc + r] = (half_t)(acc[t][r] + be);
        }
        __syncthreads();
        const int b   = rb >> 11;
        const int s0  = rb & 2047;
        const int h   = (nb >> 6) & 3;
        const int bh_ = b * NH + h;
        #pragma unroll
        for (int i = 0; i < 2; ++i) {
            int idx = tid + 256 * i;
            int rr  = idx >> 3;
            int cc8 = (idx & 7) * 8;
            *(half8*)&vt[((size_t)bh_ * DH + rr) * SS + s0 + cc8] =
                *(const half8*)&Xh[rr * KPAD + cc8];
        }
    }
}

// ---------------------------------------------------------------------------
// Flash attention, fp16 MFMA, S^T trick, split-K(2).
// Block = 256 thr (4 waves) covers 64 q rows (16 per wave); grid (32,16,2).
// 4 waves/SIMD resident (was 2): latency chain (MFMA->shfl->exp->MFMA) now
// overlapped across twice as many waves. exp2-domain softmax + defer-max
// (skip alpha/rescale while the running max grows < 8 log2-units).
// K/V tiles register-double-buffered across the compute phase.
// Writes normalized partial O (fp16) + m,l stats (m in log2 domain) per kz.
// ---------------------------------------------------------------------------
__global__ __launch_bounds__(256, 4) void attn(const half_t* __restrict__ qh,
                                               const half_t* __restrict__ kh,
                                               const half_t* __restrict__ vt,
                                               half_t* __restrict__ pO,
                                               float* __restrict__ mst,
                                               float* __restrict__ lst) {
    __shared__ __align__(16) half_t Ks[64 * KPAD];    // [kr][d]
    __shared__ __align__(16) half_t Vts[64 * KPAD];   // [d][kr]

    const int q0   = blockIdx.x * 64;
    const int bh   = blockIdx.y;
    const int kz   = blockIdx.z;
    const size_t base = (size_t)bh * SS * DH;
    const int tid  = threadIdx.x;
    const int wid  = tid >> 6;    // 0..3
    const int lane = tid & 63;
    const int quad = lane >> 4;
    const int col  = lane & 15;
    const int ktBeg = kz * (SS / 2);
    const int ktEnd = ktBeg + (SS / 2);

    int srr[2], scc[2];
    #pragma unroll
    for (int i = 0; i < 2; ++i) {
        int gi = tid + 256 * i;    // 0..511
        srr[i] = gi >> 3;          // 0..63
        scc[i] = (gi & 7) * 8;     // 0..56
    }

    // Q B-frags: one strip of 16 q rows per wave (pre-scaled by 0.125*log2e)
    half8 bq0, bq1;
    {
        int s = q0 + wid * 16 + col;
        bq0 = *(const half8*)&qh[base + (size_t)s * DH + quad * 8];
        bq1 = *(const half8*)&qh[base + (size_t)s * DH + 32 + quad * 8];
    }

    // Preload tile ktBeg into cur regs
    half8 ck[2], cv[2], nk[2], nv[2];
    #pragma unroll
    for (int i = 0; i < 2; ++i) {
        ck[i] = *(const half8*)&kh[base + (size_t)(ktBeg + srr[i]) * DH + scc[i]];
        cv[i] = *(const half8*)&vt[base + (size_t)srr[i] * SS + ktBeg + scc[i]];
        nk[i] = ck[i];
        nv[i] = cv[i];
    }

    float m_i = -3.0e38f;
    float l_i = 0.f;
    floatx4 o[4];
    #pragma unroll
    for (int dt = 0; dt < 4; ++dt) o[dt] = (floatx4){0.f, 0.f, 0.f, 0.f};

    for (int kt = ktBeg; kt < ktEnd; kt += 64) {
        __syncthreads();
        #pragma unroll
        for (int i = 0; i < 2; ++i) {
            *(half8*)&Ks[srr[i] * KPAD + scc[i]]  = ck[i];
            *(half8*)&Vts[srr[i] * KPAD + scc[i]] = cv[i];
        }
        __syncthreads();

        // Prefetch next tile (in flight across compute)
        const int ktn = kt + 64;
        if (ktn < ktEnd) {
            #pragma unroll
            for (int i = 0; i < 2; ++i) {
                nk[i] = *(const half8*)&kh[base + (size_t)(ktn + srr[i]) * DH + scc[i]];
                nv[i] = *(const half8*)&vt[base + (size_t)srr[i] * SS + ktn + scc[i]];
            }
        }

        // S^T = K · Q^T (one strip)
        floatx4 sc[4];
        #pragma unroll
        for (int t = 0; t < 4; ++t) {
            half8 ak0 = *(const half8*)&Ks[(t * 16 + col) * KPAD + quad * 8];
            half8 ak1 = *(const half8*)&Ks[(t * 16 + col) * KPAD + 32 + quad * 8];
            floatx4 c = (floatx4){0.f, 0.f, 0.f, 0.f};
            c = __builtin_amdgcn_mfma_f32_16x16x32_f16(ak0, bq0, c, 0, 0, 0);
            c = __builtin_amdgcn_mfma_f32_16x16x32_f16(ak1, bq1, c, 0, 0, 0);
            sc[t] = c;
        }

        // Online softmax (exp2 domain), defer-max rescale skip
        float mloc = -3.0e38f;
        #pragma unroll
        for (int t = 0; t < 4; ++t) {
            float a = fmaxf(fmaxf(sc[t][0], sc[t][1]), fmaxf(sc[t][2], sc[t][3]));
            mloc = fmaxf(mloc, a);
        }
        mloc = fmaxf(mloc, __shfl_xor(mloc, 16));
        mloc = fmaxf(mloc, __shfl_xor(mloc, 32));

        bool skip = __all(mloc <= m_i + DEFER_THR);
        float m_new = skip ? m_i : fmaxf(m_i, mloc);

        half4 pa[4];
        float rsum = 0.f;
        #pragma unroll
        for (int t = 0; t < 4; ++t) {
            float p0 = EXP2(sc[t][0] - m_new);
            float p1 = EXP2(sc[t][1] - m_new);
            float p2 = EXP2(sc[t][2] - m_new);
            float p3 = EXP2(sc[t][3] - m_new);
            rsum += p0 + p1 + p2 + p3;
            pa[t] = (half4){(half_t)p0, (half_t)p1, (half_t)p2, (half_t)p3};
        }
        rsum += __shfl_xor(rsum, 16);
        rsum += __shfl_xor(rsum, 32);

        if (skip) {
            l_i += rsum;
        } else {
            float alpha = EXP2(m_i - m_new);
            m_i = m_new;
            l_i = l_i * alpha + rsum;
            float ar[4];
            #pragma unroll
            for (int i = 0; i < 4; ++i) ar[i] = __shfl(alpha, quad * 4 + i);
            #pragma unroll
            for (int dt = 0; dt < 4; ++dt)
                #pragma unroll
                for (int i = 0; i < 4; ++i)
                    o[dt][i] *= ar[i];
        }

        // O += P · V
        #pragma unroll
        for (int t = 0; t < 4; ++t) {
            #pragma unroll
            for (int dt = 0; dt < 4; ++dt) {
                half4 bv = *(const half4*)&Vts[(dt * 16 + col) * KPAD + t * 16 + quad * 4];
                o[dt] = __builtin_amdgcn_mfma_f32_16x16x16f16(pa[t], bv, o[dt], 0, 0, 0);
            }
        }

        #pragma unroll
        for (int i = 0; i < 2; ++i) { ck[i] = nk[i]; cv[i] = nv[i]; }
    }

    // Epilogue: normalized partial O (fp16) + stats (m in log2 domain)
    const size_t pbase = (size_t)kz * HEAD_ELEMS + base;
    {
        float inv = 1.0f / l_i;
        float ir[4];
        #pragma unroll
        for (int i = 0; i < 4; ++i) ir[i] = __shfl(inv, quad * 4 + i);
        #pragma unroll
        for (int dt = 0; dt < 4; ++dt)
            #pragma unroll
            for (int i = 0; i < 4; ++i) {
                int row = q0 + wid * 16 + quad * 4 + i;
                pO[pbase + (size_t)row * DH + dt * 16 + col] = (half_t)(o[dt][i] * ir[i]);
            }
        if (quad == 0) {
            int row = q0 + wid * 16 + col;
            int idx = kz * NQROWS + bh * SS + row;
            mst[idx] = m_i;
            lst[idx] = l_i;
        }
    }
}

// ---------------------------------------------------------------------------
// merge: combine the two kz partials (m stats are log2-domain).
// 262144 threads, 8 d-elems each.
// ---------------------------------------------------------------------------
__global__ __launch_bounds__(256) void merge(const half_t* __restrict__ pO,
                                             const float* __restrict__ mst,
                                             const float* __restrict__ lst,
                                             float* __restrict__ out) {
    int gid = blockIdx.x * 256 + threadIdx.x;   // 0..262143
    int row = gid >> 3;                         // 0..32767 (bh*SS + s)
    int dc  = (gid & 7) * 8;
    float m1 = mst[row], m2 = mst[NQROWS + row];
    float l1 = lst[row], l2 = lst[NQROWS + row];
    float M  = fmaxf(m1, m2);
    float w1 = l1 * EXP2(m1 - M);
    float w2 = l2 * EXP2(m2 - M);
    float inv = 1.0f / (w1 + w2);
    float a = w1 * inv, b = w2 * inv;
    half8 o1 = *(const half8*)&pO[(size_t)row * DH + dc];
    half8 o2 = *(const half8*)&pO[(size_t)HEAD_ELEMS + (size_t)row * DH + dc];
    float4 r0, r1;
    r0.x = a * (float)o1[0] + b * (float)o2[0];
    r0.y = a * (float)o1[1] + b * (float)o2[1];
    r0.z = a * (float)o1[2] + b * (float)o2[2];
    r0.w = a * (float)o1[3] + b * (float)o2[3];
    r1.x = a * (float)o1[4] + b * (float)o2[4];
    r1.y = a * (float)o1[5] + b * (float)o2[5];
    r1.z = a * (float)o1[6] + b * (float)o2[6];
    r1.w = a * (float)o1[7] + b * (float)o2[7];
    *(float4*)&out[(size_t)row * DH + dc]     = r0;
    *(float4*)&out[(size_t)row * DH + dc + 4] = r1;
}

extern "C" void kernel_launch(void* const* d_in, const int* in_sizes, int n_in,
                              void* d_out, int out_size, void* d_ws, size_t ws_size,
                              hipStream_t stream) {
    const float* x  = (const float*)d_in[0];   // [4,2048,256]
    const float* Wq = (const float*)d_in[1];   // [768,256]
    const float* bq = (const float*)d_in[2];   // [768]
    float* out = (float*)d_out;                // [4,4,2048,64]

    // ws layout (half_t units):
    //   qh 0..2M | kh 2M..4M | vt 4M..6M | xh 6M..8M | xl 8M..10M | Wh 10M..10.19M
    //   pO[2] aliases xh/xl: 6M..10M (xh/xl dead once qkv_proj finishes)
    //   stats f32 after Wh region (Wh dead during attn)
    half_t* qh  = (half_t*)d_ws;
    half_t* kh  = qh + (size_t)HEAD_ELEMS;
    half_t* vt  = kh + (size_t)HEAD_ELEMS;
    half_t* xh  = vt + (size_t)HEAD_ELEMS;
    half_t* xl  = xh + (size_t)HEAD_ELEMS;
    half_t* whp = xl + (size_t)HEAD_ELEMS;             // 196608 halfs
    half_t* pO  = xh;                                  // alias: 2 x HEAD_ELEMS halfs
    float*  mst = (float*)((char*)d_ws + 21364736);    // 2*32768 floats
    float*  lst = mst + 2 * NQROWS;

    prep<<<2048, 256, 0, stream>>>(x, Wq, xh, xl, whp);
    qkv_proj<<<dim3(NROW / 64, NE / 64), 256, 0, stream>>>(xh, xl, whp, bq, qh, kh, vt);
    attn<<<dim3(SS / 64, BH, 2), 256, 0, stream>>>(qh, kh, vt, pO, mst, lst);
    merge<<<1024, 256, 0, stream>>>(pO, mst, lst, out);
}

// Round 2
// 118.731 us; speedup vs baseline: 1.0243x; 1.0010x over previous
//
#include <hip/hip_runtime.h>

// Problem constants
#define BB 4
#define SS 2048
#define DM 256
#define NH 4
#define DH 64
#define NROW (BB*SS)              // 8192
#define NE   (3*DM)               // 768
#define BH   (BB*NH)              // 16
#define HEAD_ELEMS (BH*SS*DH)     // 2097152 per tensor
#define NQROWS (BH*SS)            // 32768

typedef _Float16 half_t;
typedef __attribute__((ext_vector_type(8))) _Float16 half8;
typedef __attribute__((ext_vector_type(4))) _Float16 half4;
typedef __attribute__((ext_vector_type(4))) float floatx4;

#define KPAD 72                   // LDS stride (halfs) for [row][d] tiles
#define VPAD 136                  // LDS stride (halfs) for Vts [d][kr] tile (kr=128)

// exp2-domain softmax: scores are pre-scaled by 1/sqrt(64) * log2(e)
#define QK_SCALE 0.18033688011112042f
#define EXP2(x) __builtin_amdgcn_exp2f(x)
#define DEFER_THR 8.0f            // skip O-rescale while max grows < 8 (log2 units)

// ---------------------------------------------------------------------------
// prep: one-shot conversion  x -> (x_hi, x_lo) fp16,  W -> fp16.
// grid 2048 x 256: thread gtid handles x[gtid*4..+3]; first 49152 also W.
// ---------------------------------------------------------------------------
__global__ __launch_bounds__(256) void prep(const float* __restrict__ x,
                                            const float* __restrict__ W,
                                            half_t* __restrict__ xh,
                                            half_t* __restrict__ xl,
                                            half_t* __restrict__ wh) {
    int gtid = blockIdx.x * 256 + threadIdx.x;    // 0..524287
    {
        int i = gtid * 4;
        float4 v = *(const float4*)&x[i];
        half4 h, l;
        h.x = (half_t)v.x; l.x = (half_t)(v.x - (float)h.x);
        h.y = (half_t)v.y; l.y = (half_t)(v.y - (float)h.y);
        h.z = (half_t)v.z; l.z = (half_t)(v.z - (float)h.z);
        h.w = (half_t)v.w; l.w = (half_t)(v.w - (float)h.w);
        *(half4*)&xh[i] = h;
        *(half4*)&xl[i] = l;
    }
    if (gtid < NE * DM / 4) {
        int i = gtid * 4;
        float4 v = *(const float4*)&W[i];
        half4 h;
        h.x = (half_t)v.x; h.y = (half_t)v.y;
        h.z = (half_t)v.z; h.w = (half_t)v.w;
        *(half4*)&wh[i] = h;
    }
}

// ---------------------------------------------------------------------------
// QKV projection, fp16 MFMA, hi/lo-split x (exact x, only W rounded).
// Epilogue: q scaled by 1/8*log2e (exp2-domain attention); k scatter;
// v transposes through LDS -> coalesced vt.
// ---------------------------------------------------------------------------
__global__ __launch_bounds__(256) void qkv_proj(const half_t* __restrict__ xh,
                                                const half_t* __restrict__ xl,
                                                const half_t* __restrict__ whg,
                                                const float* __restrict__ bias,
                                                half_t* __restrict__ qh,
                                                half_t* __restrict__ kh,
                                                half_t* __restrict__ vt) {
    __shared__ __align__(16) half_t Xh[64 * KPAD];
    __shared__ __align__(16) half_t Xl[64 * KPAD];
    __shared__ __align__(16) half_t Wh[64 * KPAD];

    const int rb   = blockIdx.x * 64;
    const int nb   = blockIdx.y * 64;
    const int tid  = threadIdx.x;
    const int wid  = tid >> 6;
    const int lane = tid & 63;
    const int quad = lane >> 4;
    const int col  = lane & 15;

    floatx4 acc[4];
    #pragma unroll
    for (int t = 0; t < 4; ++t) acc[t] = (floatx4){0.f, 0.f, 0.f, 0.f};

    for (int k0 = 0; k0 < DM; k0 += 64) {
        __syncthreads();
        #pragma unroll
        for (int i = 0; i < 2; ++i) {
            int gi = tid + 256 * i;        // 0..511
            int r  = gi >> 3;              // 0..63
            int c8 = (gi & 7) * 8;         // 0..56
            *(half8*)&Xh[r * KPAD + c8] = *(const half8*)&xh[(size_t)(rb + r) * DM + k0 + c8];
            *(half8*)&Xl[r * KPAD + c8] = *(const half8*)&xl[(size_t)(rb + r) * DM + k0 + c8];
            *(half8*)&Wh[r * KPAD + c8] = *(const half8*)&whg[(size_t)(nb + r) * DM + k0 + c8];
        }
        __syncthreads();

        half8 ah0 = *(const half8*)&Xh[(wid * 16 + col) * KPAD + quad * 8];
        half8 ah1 = *(const half8*)&Xh[(wid * 16 + col) * KPAD + 32 + quad * 8];
        half8 al0 = *(const half8*)&Xl[(wid * 16 + col) * KPAD + quad * 8];
        half8 al1 = *(const half8*)&Xl[(wid * 16 + col) * KPAD + 32 + quad * 8];

        #pragma unroll
        for (int t = 0; t < 4; ++t) {
            half8 bh0 = *(const half8*)&Wh[(t * 16 + col) * KPAD + quad * 8];
            half8 bh1 = *(const half8*)&Wh[(t * 16 + col) * KPAD + 32 + quad * 8];
            acc[t] = __builtin_amdgcn_mfma_f32_16x16x32_f16(ah0, bh0, acc[t], 0, 0, 0);
            acc[t] = __builtin_amdgcn_mfma_f32_16x16x32_f16(ah1, bh1, acc[t], 0, 0, 0);
            acc[t] = __builtin_amdgcn_mfma_f32_16x16x32_f16(al0, bh0, acc[t], 0, 0, 0);
            acc[t] = __builtin_amdgcn_mfma_f32_16x16x32_f16(al1, bh1, acc[t], 0, 0, 0);
        }
    }

    const int part = nb >> 8;           // block-uniform: 0=q 1=k 2=v
    const int mloc = wid * 16 + quad * 4;
    if (part != 2) {
        #pragma unroll
        for (int t = 0; t < 4; ++t) {
            int e    = nb + t * 16 + col;
            float be = bias[e];
            int dm   = e & 255;
            int h    = dm >> 6;
            int dh   = dm & 63;
            #pragma unroll
            for (int r = 0; r < 4; ++r) {
                int row = rb + mloc + r;
                int b   = row >> 11;
                int s   = row & 2047;
                int bh_ = b * NH + h;
                float val = acc[t][r] + be;
                if (part == 0) {
                    qh[((size_t)bh_ * SS + s) * DH + dh] = (half_t)(val * QK_SCALE);
                } else {
                    kh[((size_t)bh_ * SS + s) * DH + dh] = (half_t)val;
                }
            }
        }
    } else {
        __syncthreads();
        #pragma unroll
        for (int t = 0; t < 4; ++t) {
            int e    = nb + t * 16 + col;
            float be = bias[e];
            #pragma unroll
            for (int r = 0; r < 4; ++r)
                Xh[(t * 16 + col) * KPAD + mloc + r] = (half_t)(acc[t][r] + be);
        }
        __syncthreads();
        const int b   = rb >> 11;
        const int s0  = rb & 2047;
        const int h   = (nb >> 6) & 3;
        const int bh_ = b * NH + h;
        #pragma unroll
        for (int i = 0; i < 2; ++i) {
            int idx = tid + 256 * i;
            int rr  = idx >> 3;
            int cc8 = (idx & 7) * 8;
            *(half8*)&vt[((size_t)bh_ * DH + rr) * SS + s0 + cc8] =
                *(const half8*)&Xh[rr * KPAD + cc8];
        }
    }
}

// ---------------------------------------------------------------------------
// Flash attention, fp16 MFMA, S^T trick, split-K(2), KVBLK=128.
// Block = 256 thr (4 waves) covers 64 q rows (16 per wave); grid (32,16,2).
// KVBLK=128 amortizes per-tile fixed costs (softmax reduce, 2 barriers,
// prefetch issue) over 2x the MFMA work: 16 QK + 32 PV MFMAs per tile, one
// softmax reduction for 32 scores/lane (same shuffle count as 16).
// Single nk/nv register set double-buffers K/V across the compute phase
// (write-to-LDS then overwrite with next-tile loads; WAR via waitcnt).
// exp2-domain softmax + defer-max. Writes normalized partial O + m,l stats.
// ---------------------------------------------------------------------------
__global__ __launch_bounds__(256, 4) void attn(const half_t* __restrict__ qh,
                                               const half_t* __restrict__ kh,
                                               const half_t* __restrict__ vt,
                                               half_t* __restrict__ pO,
                                               float* __restrict__ mst,
                                               float* __restrict__ lst) {
    __shared__ __align__(16) half_t Ks[128 * KPAD];   // [kr][d]   18.4 KB
    __shared__ __align__(16) half_t Vts[64 * VPAD];   // [d][kr]   17.4 KB

    const int q0   = blockIdx.x * 64;
    const int bh   = blockIdx.y;
    const int kz   = blockIdx.z;
    const size_t base = (size_t)bh * SS * DH;
    const int tid  = threadIdx.x;
    const int wid  = tid >> 6;    // 0..3
    const int lane = tid & 63;
    const int quad = lane >> 4;
    const int col  = lane & 15;
    const int ktBeg = kz * (SS / 2);
    const int ktEnd = ktBeg + (SS / 2);

    // staging maps: 4 x 256 threads x half8 = 8192 halfs per tensor
    int krr[4], kcc[4], vrr[4], vcc[4];
    #pragma unroll
    for (int i = 0; i < 4; ++i) {
        int gi = tid + 256 * i;     // 0..1023
        krr[i] = gi >> 3;           // 0..127
        kcc[i] = (gi & 7) * 8;      // 0..56
        vrr[i] = gi >> 4;           // 0..63
        vcc[i] = (gi & 15) * 8;     // 0..120
    }

    // Q B-frags: one strip of 16 q rows per wave (pre-scaled by 0.125*log2e)
    half8 bq0, bq1;
    {
        int s = q0 + wid * 16 + col;
        bq0 = *(const half8*)&qh[base + (size_t)s * DH + quad * 8];
        bq1 = *(const half8*)&qh[base + (size_t)s * DH + 32 + quad * 8];
    }

    // Preload tile ktBeg
    half8 nk[4], nv[4];
    #pragma unroll
    for (int i = 0; i < 4; ++i) {
        nk[i] = *(const half8*)&kh[base + (size_t)(ktBeg + krr[i]) * DH + kcc[i]];
        nv[i] = *(const half8*)&vt[base + (size_t)vrr[i] * SS + ktBeg + vcc[i]];
    }

    float m_i = -3.0e38f;
    float l_i = 0.f;
    floatx4 o[4];
    #pragma unroll
    for (int dt = 0; dt < 4; ++dt) o[dt] = (floatx4){0.f, 0.f, 0.f, 0.f};

    for (int kt = ktBeg; kt < ktEnd; kt += 128) {
        __syncthreads();
        #pragma unroll
        for (int i = 0; i < 4; ++i) {
            *(half8*)&Ks[krr[i] * KPAD + kcc[i]]  = nk[i];
            *(half8*)&Vts[vrr[i] * VPAD + vcc[i]] = nv[i];
        }
        __syncthreads();

        // Prefetch next tile into the same regs (in flight across compute;
        // compiler orders the overwrite after the ds_writes via waitcnt)
        const int ktn = kt + 128;
        if (ktn < ktEnd) {
            #pragma unroll
            for (int i = 0; i < 4; ++i) {
                nk[i] = *(const half8*)&kh[base + (size_t)(ktn + krr[i]) * DH + kcc[i]];
                nv[i] = *(const half8*)&vt[base + (size_t)vrr[i] * SS + ktn + vcc[i]];
            }
        }

        // S^T = K · Q^T : 128 k-rows x 16 q
        floatx4 sc[8];
        __builtin_amdgcn_s_setprio(1);
        #pragma unroll
        for (int t = 0; t < 8; ++t) {
            half8 ak0 = *(const half8*)&Ks[(t * 16 + col) * KPAD + quad * 8];
            half8 ak1 = *(const half8*)&Ks[(t * 16 + col) * KPAD + 32 + quad * 8];
            floatx4 c = (floatx4){0.f, 0.f, 0.f, 0.f};
            c = __builtin_amdgcn_mfma_f32_16x16x32_f16(ak0, bq0, c, 0, 0, 0);
            c = __builtin_amdgcn_mfma_f32_16x16x32_f16(ak1, bq1, c, 0, 0, 0);
            sc[t] = c;
        }
        __builtin_amdgcn_s_setprio(0);

        // Online softmax (exp2 domain), defer-max rescale skip
        float mloc = -3.0e38f;
        #pragma unroll
        for (int t = 0; t < 8; ++t) {
            float a = fmaxf(fmaxf(sc[t][0], sc[t][1]), fmaxf(sc[t][2], sc[t][3]));
            mloc = fmaxf(mloc, a);
        }
        mloc = fmaxf(mloc, __shfl_xor(mloc, 16));
        mloc = fmaxf(mloc, __shfl_xor(mloc, 32));

        bool skip = __all(mloc <= m_i + DEFER_THR);
        float m_new = skip ? m_i : fmaxf(m_i, mloc);

        half4 pa[8];
        float rsum = 0.f;
        #pragma unroll
        for (int t = 0; t < 8; ++t) {
            float p0 = EXP2(sc[t][0] - m_new);
            float p1 = EXP2(sc[t][1] - m_new);
            float p2 = EXP2(sc[t][2] - m_new);
            float p3 = EXP2(sc[t][3] - m_new);
            rsum += p0 + p1 + p2 + p3;
            pa[t] = (half4){(half_t)p0, (half_t)p1, (half_t)p2, (half_t)p3};
        }
        rsum += __shfl_xor(rsum, 16);
        rsum += __shfl_xor(rsum, 32);

        if (skip) {
            l_i += rsum;
        } else {
            float alpha = EXP2(m_i - m_new);
            m_i = m_new;
            l_i = l_i * alpha + rsum;
            float ar[4];
            #pragma unroll
            for (int i = 0; i < 4; ++i) ar[i] = __shfl(alpha, quad * 4 + i);
            #pragma unroll
            for (int dt = 0; dt < 4; ++dt)
                #pragma unroll
                for (int i = 0; i < 4; ++i)
                    o[dt][i] *= ar[i];
        }

        // O += P · V
        __builtin_amdgcn_s_setprio(1);
        #pragma unroll
        for (int t = 0; t < 8; ++t) {
            #pragma unroll
            for (int dt = 0; dt < 4; ++dt) {
                half4 bv = *(const half4*)&Vts[(dt * 16 + col) * VPAD + t * 16 + quad * 4];
                o[dt] = __builtin_amdgcn_mfma_f32_16x16x16f16(pa[t], bv, o[dt], 0, 0, 0);
            }
        }
        __builtin_amdgcn_s_setprio(0);
    }

    // Epilogue: normalized partial O (fp16) + stats (m in log2 domain)
    const size_t pbase = (size_t)kz * HEAD_ELEMS + base;
    {
        float inv = 1.0f / l_i;
        float ir[4];
        #pragma unroll
        for (int i = 0; i < 4; ++i) ir[i] = __shfl(inv, quad * 4 + i);
        #pragma unroll
        for (int dt = 0; dt < 4; ++dt)
            #pragma unroll
            for (int i = 0; i < 4; ++i) {
                int row = q0 + wid * 16 + quad * 4 + i;
                pO[pbase + (size_t)row * DH + dt * 16 + col] = (half_t)(o[dt][i] * ir[i]);
            }
        if (quad == 0) {
            int row = q0 + wid * 16 + col;
            int idx = kz * NQROWS + bh * SS + row;
            mst[idx] = m_i;
            lst[idx] = l_i;
        }
    }
}

// ---------------------------------------------------------------------------
// merge: combine the two kz partials (m stats are log2-domain).
// 262144 threads, 8 d-elems each.
// ---------------------------------------------------------------------------
__global__ __launch_bounds__(256) void merge(const half_t* __restrict__ pO,
                                             const float* __restrict__ mst,
                                             const float* __restrict__ lst,
                                             float* __restrict__ out) {
    int gid = blockIdx.x * 256 + threadIdx.x;   // 0..262143
    int row = gid >> 3;                         // 0..32767 (bh*SS + s)
    int dc  = (gid & 7) * 8;
    float m1 = mst[row], m2 = mst[NQROWS + row];
    float l1 = lst[row], l2 = lst[NQROWS + row];
    float M  = fmaxf(m1, m2);
    float w1 = l1 * EXP2(m1 - M);
    float w2 = l2 * EXP2(m2 - M);
    float inv = 1.0f / (w1 + w2);
    float a = w1 * inv, b = w2 * inv;
    half8 o1 = *(const half8*)&pO[(size_t)row * DH + dc];
    half8 o2 = *(const half8*)&pO[(size_t)HEAD_ELEMS + (size_t)row * DH + dc];
    float4 r0, r1;
    r0.x = a * (float)o1[0] + b * (float)o2[0];
    r0.y = a * (float)o1[1] + b * (float)o2[1];
    r0.z = a * (float)o1[2] + b * (float)o2[2];
    r0.w = a * (float)o1[3] + b * (float)o2[3];
    r1.x = a * (float)o1[4] + b * (float)o2[4];
    r1.y = a * (float)o1[5] + b * (float)o2[5];
    r1.z = a * (float)o1[6] + b * (float)o2[6];
    r1.w = a * (float)o1[7] + b * (float)o2[7];
    *(float4*)&out[(size_t)row * DH + dc]     = r0;
    *(float4*)&out[(size_t)row * DH + dc + 4] = r1;
}

extern "C" void kernel_launch(void* const* d_in, const int* in_sizes, int n_in,
                              void* d_out, int out_size, void* d_ws, size_t ws_size,
                              hipStream_t stream) {
    const float* x  = (const float*)d_in[0];   // [4,2048,256]
    const float* Wq = (const float*)d_in[1];   // [768,256]
    const float* bq = (const float*)d_in[2];   // [768]
    float* out = (float*)d_out;                // [4,4,2048,64]

    // ws layout (half_t units):
    //   qh 0..2M | kh 2M..4M | vt 4M..6M | xh 6M..8M | xl 8M..10M | Wh 10M..10.19M
    //   pO[2] aliases xh/xl: 6M..10M (xh/xl dead once qkv_proj finishes)
    //   stats f32 after Wh region (Wh dead during attn)
    half_t* qh  = (half_t*)d_ws;
    half_t* kh  = qh + (size_t)HEAD_ELEMS;
    half_t* vt  = kh + (size_t)HEAD_ELEMS;
    half_t* xh  = vt + (size_t)HEAD_ELEMS;
    half_t* xl  = xh + (size_t)HEAD_ELEMS;
    half_t* whp = xl + (size_t)HEAD_ELEMS;             // 196608 halfs
    half_t* pO  = xh;                                  // alias: 2 x HEAD_ELEMS halfs
    float*  mst = (float*)((char*)d_ws + 21364736);    // 2*32768 floats
    float*  lst = mst + 2 * NQROWS;

    prep<<<2048, 256, 0, stream>>>(x, Wq, xh, xl, whp);
    qkv_proj<<<dim3(NROW / 64, NE / 64), 256, 0, stream>>>(xh, xl, whp, bq, qh, kh, vt);
    attn<<<dim3(SS / 64, BH, 2), 256, 0, stream>>>(qh, kh, vt, pO, mst, lst);
    merge<<<1024, 256, 0, stream>>>(pO, mst, lst, out);
}